// Round 6
// baseline (103.575 us; speedup 1.0000x reference)
//
#include <hip/hip_runtime.h>
#include <hip/hip_bf16.h>

#define N_POINTS 16384
#define N_GAUSS  3200
#define N_CLASSES 14
#define P2_STRIDE 10            // floats per gaussian coeff record
#define NCHUNK (N_GAUSS / 32)   // 100 K-chunks of 32 gaussians

typedef _Float16 half8  __attribute__((ext_vector_type(8)));   // 4 VGPRs
typedef _Float16 half2v __attribute__((ext_vector_type(2)));
typedef float    f32x4  __attribute__((ext_vector_type(4)));

// d_ws layout (total exactly 307,200 B -- proven safe):
//   [0, 128000)         p2:   [3200][10] f32
//   [128000, 217600)    semH: [14][3200] f16   (hi part of semantics)
//   [217600, 307200)    semL: [14][3200] f16   (residual part)
#define WS_P2_OFF   0
#define WS_SEMH_OFF 128000
#define WS_SEML_OFF 217600

// ---------------------------------------------------------------------------
// Prep: per-gaussian quadratic-form coefficients in "P-form":
//   arg = Sum_{k=0..8} P[k]*C[k] + C9,   P = [x^2,y^2,z^2,xy,xz,yz,x,y,z]
//   exp2(arg) = opacity * exp(-0.5*q).
// Semantics transposed to f16 hi+lo pairs: sem = semH + semL (to ~2^-22 rel).
// ---------------------------------------------------------------------------
__global__ void gauss_prep_kernel(const float* __restrict__ means,
                                  const float* __restrict__ scales,
                                  const float* __restrict__ rotations,
                                  const float* __restrict__ opacities,
                                  const float* __restrict__ semantics,
                                  float* __restrict__ p2,
                                  _Float16* __restrict__ semH,
                                  _Float16* __restrict__ semL) {
    int g = blockIdx.x * blockDim.x + threadIdx.x;
    if (g >= N_GAUSS) return;

    float qw = rotations[g * 4 + 0];
    float qx = rotations[g * 4 + 1];
    float qy = rotations[g * 4 + 2];
    float qz = rotations[g * 4 + 3];
    float inv = 1.0f / sqrtf(qw * qw + qx * qx + qy * qy + qz * qz);
    qw *= inv; qx *= inv; qy *= inv; qz *= inv;

    float r00 = 1.0f - 2.0f * (qy * qy + qz * qz);
    float r01 = 2.0f * (qx * qy - qw * qz);
    float r02 = 2.0f * (qx * qz + qw * qy);
    float r10 = 2.0f * (qx * qy + qw * qz);
    float r11 = 1.0f - 2.0f * (qx * qx + qz * qz);
    float r12 = 2.0f * (qy * qz - qw * qx);
    float r20 = 2.0f * (qx * qz - qw * qy);
    float r21 = 2.0f * (qy * qz + qw * qx);
    float r22 = 1.0f - 2.0f * (qx * qx + qy * qy);

    float sx = scales[g * 3 + 0];
    float sy = scales[g * 3 + 1];
    float sz = scales[g * 3 + 2];
    float iv0 = 1.0f / (sx * sx);
    float iv1 = 1.0f / (sy * sy);
    float iv2 = 1.0f / (sz * sz);

    float a00 = iv0 * r00 * r00 + iv1 * r10 * r10 + iv2 * r20 * r20;
    float a01 = iv0 * r00 * r01 + iv1 * r10 * r11 + iv2 * r20 * r21;
    float a02 = iv0 * r00 * r02 + iv1 * r10 * r12 + iv2 * r20 * r22;
    float a11 = iv0 * r01 * r01 + iv1 * r11 * r11 + iv2 * r21 * r21;
    float a12 = iv0 * r01 * r02 + iv1 * r11 * r12 + iv2 * r21 * r22;
    float a22 = iv0 * r02 * r02 + iv1 * r12 * r12 + iv2 * r22 * r22;

    float mx = means[g * 3 + 0];
    float my = means[g * 3 + 1];
    float mz = means[g * 3 + 2];
    float amx = a00 * mx + a01 * my + a02 * mz;
    float amy = a01 * mx + a11 * my + a12 * mz;
    float amz = a02 * mx + a12 * my + a22 * mz;
    float muAmu = mx * amx + my * amy + mz * amz;

    const float k = -0.72134752044448170368f;   // -0.5 * log2(e)

    float* p = p2 + (size_t)g * P2_STRIDE;
    p[0] = k * a00;
    p[1] = k * a11;
    p[2] = k * a22;
    p[3] = 2.0f * k * a01;
    p[4] = 2.0f * k * a02;
    p[5] = 2.0f * k * a12;
    p[6] = -2.0f * k * amx;
    p[7] = -2.0f * k * amy;
    p[8] = -2.0f * k * amz;
    p[9] = k * muAmu + log2f(opacities[g]);

#pragma unroll
    for (int c = 0; c < N_CLASSES; ++c) {
        float v = semantics[g * N_CLASSES + c];
        _Float16 h = (_Float16)v;            // RNE, rel 2^-12
        float res = v - (float)h;            // exact
        semH[(size_t)c * N_GAUSS + g] = h;
        semL[(size_t)c * N_GAUSS + g] = (_Float16)res;
    }
}

// ---------------------------------------------------------------------------
// Main: 1024 blocks (256 point-groups x 4 splits) x 512 threads (8 waves),
// pinned at 4 blocks/CU (8 waves/SIMD). Wave slot = split*8+wid owns 3-4
// K-chunks of 32 gaussians. Per chunk: each lane computes w=exp2(arg) for
// its point x 32 gaussians (wave-uniform s_loads; NO inline-asm waits, so
// the compiler keeps the scalar-load pipeline running across chunks),
// packs to f16 RNE, stages once in wave-private LDS (XOR-swizzled 16B
// blocks), then 4 A-frag reads feed 8 MFMAs: w*semH + w*semL (sem hi/lo
// carries precision; B-lanes for classes 14/15 clamp to 13, producing
// discarded duplicate columns instead of a divergent zero-fill branch).
// Epilogue: LDS 8-way reduce (aliased buffer) + one fp32 atomic/elem.
// ---------------------------------------------------------------------------
__launch_bounds__(512, 8)
__global__ void gauss_occ_main_kernel(const float* __restrict__ xyz,
                                      const float* __restrict__ p2,
                                      const _Float16* __restrict__ semH,
                                      const _Float16* __restrict__ semL,
                                      float* __restrict__ out) {
    __shared__ unsigned int wbuf[8][64][16];   // 32 KiB: per-wave 4 KiB w-tile; aliased as reduce buf

    const int tid  = threadIdx.x;
    const int lane = tid & 63;
    const int wid  = tid >> 6;
    const int pg    = blockIdx.x >> 2;
    const int split = blockIdx.x & 3;
    const int slot  = split * 8 + wid;               // 0..31
    const int c0 = (slot * NCHUNK) >> 5;
    const int c1 = ((slot + 1) * NCHUNK) >> 5;

    const int m   = lane & 15;      // fragment row/col id
    const int mm  = (m < N_CLASSES) ? m : (N_CLASSES - 1);  // B-row clamp (cols 14/15 discarded)
    const int grp = lane >> 4;      // k-group 0..3
    const int frs = (m >> 1) & 3;   // read-side swizzle
    const int wsz = (lane >> 1) & 3;// write-side swizzle

    const int pt = pg * 64 + lane;
    const float x = xyz[pt * 3 + 0];
    const float y = xyz[pt * 3 + 1];
    const float z = xyz[pt * 3 + 2];
    const float P0 = x * x, P1 = y * y, P2 = z * z;
    const float P3 = x * y, P4 = x * z, P5 = y * z;

    f32x4 acc0 = {0.f, 0.f, 0.f, 0.f};
    f32x4 acc1 = {0.f, 0.f, 0.f, 0.f};
    f32x4 acc2 = {0.f, 0.f, 0.f, 0.f};
    f32x4 acc3 = {0.f, 0.f, 0.f, 0.f};

    unsigned int (*wrow)[16] = wbuf[wid];

    for (int c = c0; c < c1; ++c) {
        const int g0 = c * 32;

        // B fragments: lane reads sem[clamped class][g0 + grp*8 .. +7]
        const half8 bH = *(const half8*)(semH + (size_t)mm * N_GAUSS + g0 + grp * 8);
        const half8 bL = *(const half8*)(semL + (size_t)mm * N_GAUSS + g0 + grp * 8);

        // ---- compute 32 w's, pack as f16 pairs (RNE) ----
        unsigned int wpk[16];
#pragma unroll
        for (int t = 0; t < 16; ++t) {
            const float* ga = p2 + (size_t)(g0 + 2 * t) * P2_STRIDE;  // wave-uniform -> s_load
            const float* gb = ga + P2_STRIDE;
            float q0 = ga[9];
            q0 = fmaf(P0, ga[0], q0); q0 = fmaf(P1, ga[1], q0); q0 = fmaf(P2, ga[2], q0);
            q0 = fmaf(P3, ga[3], q0); q0 = fmaf(P4, ga[4], q0); q0 = fmaf(P5, ga[5], q0);
            q0 = fmaf(x,  ga[6], q0); q0 = fmaf(y,  ga[7], q0); q0 = fmaf(z,  ga[8], q0);
            float q1 = gb[9];
            q1 = fmaf(P0, gb[0], q1); q1 = fmaf(P1, gb[1], q1); q1 = fmaf(P2, gb[2], q1);
            q1 = fmaf(P3, gb[3], q1); q1 = fmaf(P4, gb[4], q1); q1 = fmaf(P5, gb[5], q1);
            q1 = fmaf(x,  gb[6], q1); q1 = fmaf(y,  gb[7], q1); q1 = fmaf(z,  gb[8], q1);
            half2v hv;
            hv[0] = (_Float16)__builtin_amdgcn_exp2f(q0);   // v_cvt_f16_f32 (RNE)
            hv[1] = (_Float16)__builtin_amdgcn_exp2f(q1);
            wpk[t] = __builtin_bit_cast(unsigned int, hv);
        }

        // ---- stage (once): row = lane, 16B block (sb ^ wsz) ----
#pragma unroll
        for (int sb = 0; sb < 4; ++sb) {
            *(uint4*)&wrow[lane][(sb ^ wsz) * 4] =
                make_uint4(wpk[4 * sb + 0], wpk[4 * sb + 1], wpk[4 * sb + 2], wpk[4 * sb + 3]);
        }

        // ---- A-frag reads + 8 MFMAs (compiler inserts precise lgkmcnt) ----
        const half8 a0 = *(const half8*)&wrow[ 0 + m][(grp ^ frs) * 4];
        const half8 a1 = *(const half8*)&wrow[16 + m][(grp ^ frs) * 4];
        const half8 a2 = *(const half8*)&wrow[32 + m][(grp ^ frs) * 4];
        const half8 a3 = *(const half8*)&wrow[48 + m][(grp ^ frs) * 4];
        acc0 = __builtin_amdgcn_mfma_f32_16x16x32_f16(a0, bH, acc0, 0, 0, 0);
        acc1 = __builtin_amdgcn_mfma_f32_16x16x32_f16(a1, bH, acc1, 0, 0, 0);
        acc2 = __builtin_amdgcn_mfma_f32_16x16x32_f16(a2, bH, acc2, 0, 0, 0);
        acc3 = __builtin_amdgcn_mfma_f32_16x16x32_f16(a3, bH, acc3, 0, 0, 0);
        acc0 = __builtin_amdgcn_mfma_f32_16x16x32_f16(a0, bL, acc0, 0, 0, 0);
        acc1 = __builtin_amdgcn_mfma_f32_16x16x32_f16(a1, bL, acc1, 0, 0, 0);
        acc2 = __builtin_amdgcn_mfma_f32_16x16x32_f16(a2, bL, acc2, 0, 0, 0);
        acc3 = __builtin_amdgcn_mfma_f32_16x16x32_f16(a3, bL, acc3, 0, 0, 0);
    }

    // ---- epilogue: dump acc into (aliased) LDS, 8-way reduce, atomics ----
    __syncthreads();   // all waves done with their w-tiles before aliasing
    float* red = (float*)&wbuf[0][0][0];   // [8][64][16] f32
#pragma unroll
    for (int i = 0; i < 4; ++i) {
        red[wid * 1024 + ( 0 + grp * 4 + i) * 16 + m] = acc0[i];
        red[wid * 1024 + (16 + grp * 4 + i) * 16 + m] = acc1[i];
        red[wid * 1024 + (32 + grp * 4 + i) * 16 + m] = acc2[i];
        red[wid * 1024 + (48 + grp * 4 + i) * 16 + m] = acc3[i];
    }
    __syncthreads();

    for (int idx = tid; idx < 64 * N_CLASSES; idx += 512) {
        const int l = idx / N_CLASSES;
        const int cc = idx - l * N_CLASSES;
        float s = 0.0f;
#pragma unroll
        for (int wq = 0; wq < 8; ++wq) s += red[wq * 1024 + l * 16 + cc];
        unsafeAtomicAdd(&out[(pg * 64 + l) * N_CLASSES + cc], s);
    }
}

extern "C" void kernel_launch(void* const* d_in, const int* in_sizes, int n_in,
                              void* d_out, int out_size, void* d_ws, size_t ws_size,
                              hipStream_t stream) {
    const float* xyz       = (const float*)d_in[0];
    const float* means     = (const float*)d_in[1];
    const float* scales    = (const float*)d_in[2];
    const float* rotations = (const float*)d_in[3];
    const float* opacities = (const float*)d_in[4];
    const float* semantics = (const float*)d_in[5];
    float* out = (float*)d_out;

    float*    p2   = (float*)((char*)d_ws + WS_P2_OFF);
    _Float16* semH = (_Float16*)((char*)d_ws + WS_SEMH_OFF);
    _Float16* semL = (_Float16*)((char*)d_ws + WS_SEML_OFF);

    (void)hipMemsetAsync(d_out, 0, (size_t)out_size * sizeof(float), stream);

    hipLaunchKernelGGL(gauss_prep_kernel,
                       dim3((N_GAUSS + 255) / 256), dim3(256), 0, stream,
                       means, scales, rotations, opacities, semantics, p2, semH, semL);

    hipLaunchKernelGGL(gauss_occ_main_kernel,
                       dim3(256 * 4), dim3(512), 0, stream,
                       xyz, p2, semH, semL, out);
}

// Round 7
// 82.184 us; speedup vs baseline: 1.2603x; 1.2603x over previous
//
#include <hip/hip_runtime.h>
#include <hip/hip_bf16.h>

#define N_POINTS 16384
#define N_GAUSS  3200
#define N_CLASSES 14
#define P2_STRIDE 10            // floats per gaussian coeff record
#define NCHUNK (N_GAUSS / 32)   // 100 K-chunks of 32 gaussians

typedef _Float16 half8  __attribute__((ext_vector_type(8)));   // 4 VGPRs
typedef _Float16 half2v __attribute__((ext_vector_type(2)));
typedef float    f32x4  __attribute__((ext_vector_type(4)));

// d_ws layout (total exactly 307,200 B -- proven safe):
//   [0, 128000)         p2:   [3200][10] f32
//   [128000, 217600)    semH: [14][3200] f16   (hi part of semantics)
//   [217600, 307200)    semL: [14][3200] f16   (residual part)
#define WS_P2_OFF   0
#define WS_SEMH_OFF 128000
#define WS_SEML_OFF 217600

// ---------------------------------------------------------------------------
// Prep: per-gaussian quadratic-form coefficients in "P-form":
//   arg = Sum_{k=0..8} P[k]*C[k] + C9,   P = [x^2,y^2,z^2,xy,xz,yz,x,y,z]
//   exp2(arg) = opacity * exp(-0.5*q).
// Semantics transposed to f16 hi+lo pairs: sem = semH + semL (to ~2^-22 rel).
// ---------------------------------------------------------------------------
__global__ void gauss_prep_kernel(const float* __restrict__ means,
                                  const float* __restrict__ scales,
                                  const float* __restrict__ rotations,
                                  const float* __restrict__ opacities,
                                  const float* __restrict__ semantics,
                                  float* __restrict__ p2,
                                  _Float16* __restrict__ semH,
                                  _Float16* __restrict__ semL) {
    int g = blockIdx.x * blockDim.x + threadIdx.x;
    if (g >= N_GAUSS) return;

    float qw = rotations[g * 4 + 0];
    float qx = rotations[g * 4 + 1];
    float qy = rotations[g * 4 + 2];
    float qz = rotations[g * 4 + 3];
    float inv = 1.0f / sqrtf(qw * qw + qx * qx + qy * qy + qz * qz);
    qw *= inv; qx *= inv; qy *= inv; qz *= inv;

    float r00 = 1.0f - 2.0f * (qy * qy + qz * qz);
    float r01 = 2.0f * (qx * qy - qw * qz);
    float r02 = 2.0f * (qx * qz + qw * qy);
    float r10 = 2.0f * (qx * qy + qw * qz);
    float r11 = 1.0f - 2.0f * (qx * qx + qz * qz);
    float r12 = 2.0f * (qy * qz - qw * qx);
    float r20 = 2.0f * (qx * qz - qw * qy);
    float r21 = 2.0f * (qy * qz + qw * qx);
    float r22 = 1.0f - 2.0f * (qx * qx + qy * qy);

    float sx = scales[g * 3 + 0];
    float sy = scales[g * 3 + 1];
    float sz = scales[g * 3 + 2];
    float iv0 = 1.0f / (sx * sx);
    float iv1 = 1.0f / (sy * sy);
    float iv2 = 1.0f / (sz * sz);

    float a00 = iv0 * r00 * r00 + iv1 * r10 * r10 + iv2 * r20 * r20;
    float a01 = iv0 * r00 * r01 + iv1 * r10 * r11 + iv2 * r20 * r21;
    float a02 = iv0 * r00 * r02 + iv1 * r10 * r12 + iv2 * r20 * r22;
    float a11 = iv0 * r01 * r01 + iv1 * r11 * r11 + iv2 * r21 * r21;
    float a12 = iv0 * r01 * r02 + iv1 * r11 * r12 + iv2 * r21 * r22;
    float a22 = iv0 * r02 * r02 + iv1 * r12 * r12 + iv2 * r22 * r22;

    float mx = means[g * 3 + 0];
    float my = means[g * 3 + 1];
    float mz = means[g * 3 + 2];
    float amx = a00 * mx + a01 * my + a02 * mz;
    float amy = a01 * mx + a11 * my + a12 * mz;
    float amz = a02 * mx + a12 * my + a22 * mz;
    float muAmu = mx * amx + my * amy + mz * amz;

    const float k = -0.72134752044448170368f;   // -0.5 * log2(e)

    float* p = p2 + (size_t)g * P2_STRIDE;
    p[0] = k * a00;
    p[1] = k * a11;
    p[2] = k * a22;
    p[3] = 2.0f * k * a01;
    p[4] = 2.0f * k * a02;
    p[5] = 2.0f * k * a12;
    p[6] = -2.0f * k * amx;
    p[7] = -2.0f * k * amy;
    p[8] = -2.0f * k * amz;
    p[9] = k * muAmu + log2f(opacities[g]);

#pragma unroll
    for (int c = 0; c < N_CLASSES; ++c) {
        float v = semantics[g * N_CLASSES + c];
        _Float16 h = (_Float16)v;            // RNE, rel 2^-12
        float res = v - (float)h;            // exact
        semH[(size_t)c * N_GAUSS + g] = h;
        semL[(size_t)c * N_GAUSS + g] = (_Float16)res;
    }
}

// ---------------------------------------------------------------------------
// Main: 1024 blocks (256 point-groups x 4 splits) x 512 threads (8 waves).
// __launch_bounds__(512, 4): cap 128 VGPR -- R6's (512,8) forced a 32-VGPR
// cap and spilled wpk[16]+acc to scratch (FETCH 733KB -> 34.8MB). R5 proved
// 56 VGPR / no spill at this bound.
// Wave slot = split*8+wid owns 3-4 K-chunks of 32 gaussians. Per chunk:
// each lane computes w=exp2(arg) for its point x 32 gaussians (wave-uniform
// s_loads; no inline-asm waits -- R5 showed full lgkmcnt drains serialize
// the scalar-load pipeline), packs to f16 RNE, stages once in wave-private
// LDS (XOR-swizzled 16B blocks), then 4 A-frag reads feed 8 MFMAs:
// w*semH + w*semL (sem hi/lo carries precision; B-lanes for classes 14/15
// clamp to 13, producing discarded duplicate columns instead of a divergent
// zero-fill). Epilogue: LDS 8-way reduce (own region) + one fp32 atomic/elem.
// ---------------------------------------------------------------------------
__launch_bounds__(512, 4)
__global__ void gauss_occ_main_kernel(const float* __restrict__ xyz,
                                      const float* __restrict__ p2,
                                      const _Float16* __restrict__ semH,
                                      const _Float16* __restrict__ semL,
                                      float* __restrict__ out) {
    __shared__ unsigned int wbuf[8][64][16];   // 32 KiB: per-wave 4 KiB w-tile; aliased as reduce buf

    const int tid  = threadIdx.x;
    const int lane = tid & 63;
    const int wid  = tid >> 6;
    const int pg    = blockIdx.x >> 2;
    const int split = blockIdx.x & 3;
    const int slot  = split * 8 + wid;               // 0..31
    const int c0 = (slot * NCHUNK) >> 5;
    const int c1 = ((slot + 1) * NCHUNK) >> 5;

    const int m   = lane & 15;      // fragment row/col id
    const int mm  = (m < N_CLASSES) ? m : (N_CLASSES - 1);  // B-row clamp (cols 14/15 discarded)
    const int grp = lane >> 4;      // k-group 0..3
    const int frs = (m >> 1) & 3;   // read-side swizzle
    const int wsz = (lane >> 1) & 3;// write-side swizzle

    const int pt = pg * 64 + lane;
    const float x = xyz[pt * 3 + 0];
    const float y = xyz[pt * 3 + 1];
    const float z = xyz[pt * 3 + 2];
    const float P0 = x * x, P1 = y * y, P2 = z * z;
    const float P3 = x * y, P4 = x * z, P5 = y * z;

    f32x4 acc0 = {0.f, 0.f, 0.f, 0.f};
    f32x4 acc1 = {0.f, 0.f, 0.f, 0.f};
    f32x4 acc2 = {0.f, 0.f, 0.f, 0.f};
    f32x4 acc3 = {0.f, 0.f, 0.f, 0.f};

    unsigned int (*wrow)[16] = wbuf[wid];

    for (int c = c0; c < c1; ++c) {
        const int g0 = c * 32;

        // B fragments: lane reads sem[clamped class][g0 + grp*8 .. +7]
        const half8 bH = *(const half8*)(semH + (size_t)mm * N_GAUSS + g0 + grp * 8);
        const half8 bL = *(const half8*)(semL + (size_t)mm * N_GAUSS + g0 + grp * 8);

        // ---- compute 32 w's, pack as f16 pairs (RNE) ----
        unsigned int wpk[16];
#pragma unroll
        for (int t = 0; t < 16; ++t) {
            const float* ga = p2 + (size_t)(g0 + 2 * t) * P2_STRIDE;  // wave-uniform -> s_load
            const float* gb = ga + P2_STRIDE;
            float q0 = ga[9];
            q0 = fmaf(P0, ga[0], q0); q0 = fmaf(P1, ga[1], q0); q0 = fmaf(P2, ga[2], q0);
            q0 = fmaf(P3, ga[3], q0); q0 = fmaf(P4, ga[4], q0); q0 = fmaf(P5, ga[5], q0);
            q0 = fmaf(x,  ga[6], q0); q0 = fmaf(y,  ga[7], q0); q0 = fmaf(z,  ga[8], q0);
            float q1 = gb[9];
            q1 = fmaf(P0, gb[0], q1); q1 = fmaf(P1, gb[1], q1); q1 = fmaf(P2, gb[2], q1);
            q1 = fmaf(P3, gb[3], q1); q1 = fmaf(P4, gb[4], q1); q1 = fmaf(P5, gb[5], q1);
            q1 = fmaf(x,  gb[6], q1); q1 = fmaf(y,  gb[7], q1); q1 = fmaf(z,  gb[8], q1);
            half2v hv;
            hv[0] = (_Float16)__builtin_amdgcn_exp2f(q0);   // v_cvt_f16_f32 (RNE)
            hv[1] = (_Float16)__builtin_amdgcn_exp2f(q1);
            wpk[t] = __builtin_bit_cast(unsigned int, hv);
        }

        // ---- stage (once): row = lane, 16B block (sb ^ wsz) ----
#pragma unroll
        for (int sb = 0; sb < 4; ++sb) {
            *(uint4*)&wrow[lane][(sb ^ wsz) * 4] =
                make_uint4(wpk[4 * sb + 0], wpk[4 * sb + 1], wpk[4 * sb + 2], wpk[4 * sb + 3]);
        }

        // ---- A-frag reads + 8 MFMAs (compiler inserts precise lgkmcnt) ----
        const half8 a0 = *(const half8*)&wrow[ 0 + m][(grp ^ frs) * 4];
        const half8 a1 = *(const half8*)&wrow[16 + m][(grp ^ frs) * 4];
        const half8 a2 = *(const half8*)&wrow[32 + m][(grp ^ frs) * 4];
        const half8 a3 = *(const half8*)&wrow[48 + m][(grp ^ frs) * 4];
        acc0 = __builtin_amdgcn_mfma_f32_16x16x32_f16(a0, bH, acc0, 0, 0, 0);
        acc1 = __builtin_amdgcn_mfma_f32_16x16x32_f16(a1, bH, acc1, 0, 0, 0);
        acc2 = __builtin_amdgcn_mfma_f32_16x16x32_f16(a2, bH, acc2, 0, 0, 0);
        acc3 = __builtin_amdgcn_mfma_f32_16x16x32_f16(a3, bH, acc3, 0, 0, 0);
        acc0 = __builtin_amdgcn_mfma_f32_16x16x32_f16(a0, bL, acc0, 0, 0, 0);
        acc1 = __builtin_amdgcn_mfma_f32_16x16x32_f16(a1, bL, acc1, 0, 0, 0);
        acc2 = __builtin_amdgcn_mfma_f32_16x16x32_f16(a2, bL, acc2, 0, 0, 0);
        acc3 = __builtin_amdgcn_mfma_f32_16x16x32_f16(a3, bL, acc3, 0, 0, 0);
    }

    // ---- epilogue: dump acc into own LDS region, 8-way reduce, atomics ----
    float* red = (float*)&wbuf[0][0][0];   // [8][64][16] f32; wave wid's region == its wbuf
#pragma unroll
    for (int i = 0; i < 4; ++i) {
        red[wid * 1024 + ( 0 + grp * 4 + i) * 16 + m] = acc0[i];
        red[wid * 1024 + (16 + grp * 4 + i) * 16 + m] = acc1[i];
        red[wid * 1024 + (32 + grp * 4 + i) * 16 + m] = acc2[i];
        red[wid * 1024 + (48 + grp * 4 + i) * 16 + m] = acc3[i];
    }
    __syncthreads();

    for (int idx = tid; idx < 64 * N_CLASSES; idx += 512) {
        const int l = idx / N_CLASSES;
        const int cc = idx - l * N_CLASSES;
        float s = 0.0f;
#pragma unroll
        for (int wq = 0; wq < 8; ++wq) s += red[wq * 1024 + l * 16 + cc];
        unsafeAtomicAdd(&out[(pg * 64 + l) * N_CLASSES + cc], s);
    }
}

extern "C" void kernel_launch(void* const* d_in, const int* in_sizes, int n_in,
                              void* d_out, int out_size, void* d_ws, size_t ws_size,
                              hipStream_t stream) {
    const float* xyz       = (const float*)d_in[0];
    const float* means     = (const float*)d_in[1];
    const float* scales    = (const float*)d_in[2];
    const float* rotations = (const float*)d_in[3];
    const float* opacities = (const float*)d_in[4];
    const float* semantics = (const float*)d_in[5];
    float* out = (float*)d_out;

    float*    p2   = (float*)((char*)d_ws + WS_P2_OFF);
    _Float16* semH = (_Float16*)((char*)d_ws + WS_SEMH_OFF);
    _Float16* semL = (_Float16*)((char*)d_ws + WS_SEML_OFF);

    (void)hipMemsetAsync(d_out, 0, (size_t)out_size * sizeof(float), stream);

    hipLaunchKernelGGL(gauss_prep_kernel,
                       dim3((N_GAUSS + 255) / 256), dim3(256), 0, stream,
                       means, scales, rotations, opacities, semantics, p2, semH, semL);

    hipLaunchKernelGGL(gauss_occ_main_kernel,
                       dim3(256 * 4), dim3(512), 0, stream,
                       xyz, p2, semH, semL, out);
}

// Round 8
// 45.547 us; speedup vs baseline: 2.2740x; 1.8044x over previous
//
#include <hip/hip_runtime.h>
#include <hip/hip_bf16.h>

#define N_POINTS 16384
#define N_GAUSS  3200
#define N_CLASSES 14
#define P2_STRIDE 10            // floats per gaussian coeff record
#define NCHUNK (N_GAUSS / 32)   // 100 K-chunks of 32 gaussians

typedef _Float16 half8  __attribute__((ext_vector_type(8)));   // 4 VGPRs
typedef _Float16 half2v __attribute__((ext_vector_type(2)));
typedef float    f32x4  __attribute__((ext_vector_type(4)));

// d_ws layout (total exactly 307,200 B -- proven safe):
//   [0, 128000)         p2:   [3200][10] f32
//   [128000, 217600)    semH: [14][3200] f16   (hi part of semantics)
//   [217600, 307200)    semL: [14][3200] f16   (residual part)
#define WS_P2_OFF   0
#define WS_SEMH_OFF 128000
#define WS_SEML_OFF 217600

// ---------------------------------------------------------------------------
// Prep: per-gaussian quadratic-form coefficients in "P-form":
//   arg = Sum_{k=0..8} P[k]*C[k] + C9,   P = [x^2,y^2,z^2,xy,xz,yz,x,y,z]
//   exp2(arg) = opacity * exp(-0.5*q).
// Semantics transposed to f16 hi+lo pairs: sem = semH + semL (to ~2^-22 rel).
// ---------------------------------------------------------------------------
__global__ void gauss_prep_kernel(const float* __restrict__ means,
                                  const float* __restrict__ scales,
                                  const float* __restrict__ rotations,
                                  const float* __restrict__ opacities,
                                  const float* __restrict__ semantics,
                                  float* __restrict__ p2,
                                  _Float16* __restrict__ semH,
                                  _Float16* __restrict__ semL) {
    int g = blockIdx.x * blockDim.x + threadIdx.x;
    if (g >= N_GAUSS) return;

    float qw = rotations[g * 4 + 0];
    float qx = rotations[g * 4 + 1];
    float qy = rotations[g * 4 + 2];
    float qz = rotations[g * 4 + 3];
    float inv = 1.0f / sqrtf(qw * qw + qx * qx + qy * qy + qz * qz);
    qw *= inv; qx *= inv; qy *= inv; qz *= inv;

    float r00 = 1.0f - 2.0f * (qy * qy + qz * qz);
    float r01 = 2.0f * (qx * qy - qw * qz);
    float r02 = 2.0f * (qx * qz + qw * qy);
    float r10 = 2.0f * (qx * qy + qw * qz);
    float r11 = 1.0f - 2.0f * (qx * qx + qz * qz);
    float r12 = 2.0f * (qy * qz - qw * qx);
    float r20 = 2.0f * (qx * qz - qw * qy);
    float r21 = 2.0f * (qy * qz + qw * qx);
    float r22 = 1.0f - 2.0f * (qx * qx + qy * qy);

    float sx = scales[g * 3 + 0];
    float sy = scales[g * 3 + 1];
    float sz = scales[g * 3 + 2];
    float iv0 = 1.0f / (sx * sx);
    float iv1 = 1.0f / (sy * sy);
    float iv2 = 1.0f / (sz * sz);

    float a00 = iv0 * r00 * r00 + iv1 * r10 * r10 + iv2 * r20 * r20;
    float a01 = iv0 * r00 * r01 + iv1 * r10 * r11 + iv2 * r20 * r21;
    float a02 = iv0 * r00 * r02 + iv1 * r10 * r12 + iv2 * r20 * r22;
    float a11 = iv0 * r01 * r01 + iv1 * r11 * r11 + iv2 * r21 * r21;
    float a12 = iv0 * r01 * r02 + iv1 * r11 * r12 + iv2 * r21 * r22;
    float a22 = iv0 * r02 * r02 + iv1 * r12 * r12 + iv2 * r22 * r22;

    float mx = means[g * 3 + 0];
    float my = means[g * 3 + 1];
    float mz = means[g * 3 + 2];
    float amx = a00 * mx + a01 * my + a02 * mz;
    float amy = a01 * mx + a11 * my + a12 * mz;
    float amz = a02 * mx + a12 * my + a22 * mz;
    float muAmu = mx * amx + my * amy + mz * amz;

    const float k = -0.72134752044448170368f;   // -0.5 * log2(e)

    float* p = p2 + (size_t)g * P2_STRIDE;
    p[0] = k * a00;
    p[1] = k * a11;
    p[2] = k * a22;
    p[3] = 2.0f * k * a01;
    p[4] = 2.0f * k * a02;
    p[5] = 2.0f * k * a12;
    p[6] = -2.0f * k * amx;
    p[7] = -2.0f * k * amy;
    p[8] = -2.0f * k * amz;
    p[9] = k * muAmu + log2f(opacities[g]);

#pragma unroll
    for (int c = 0; c < N_CLASSES; ++c) {
        float v = semantics[g * N_CLASSES + c];
        _Float16 h = (_Float16)v;            // RNE, rel 2^-12
        float res = v - (float)h;            // exact
        semH[(size_t)c * N_GAUSS + g] = h;
        semL[(size_t)c * N_GAUSS + g] = (_Float16)res;
    }
}

// ---------------------------------------------------------------------------
// Main: 1024 blocks (256 point-groups x 4 splits) x 512 threads (8 waves).
// CRITICAL: wid goes through readfirstlane so slot/c0/c1 and all p2
// addresses are PROVABLY wave-uniform -> coefficients load via s_load
// (SGPR pipeline, deep prefetch). R3-R7 dropped this; coefficient loads
// fell to per-lane VMEM (SGPR_Count 80 -> 32) and the kernel went
// latency-bound at 24% VALUBusy, 74.6us. R2 (with readfirstlane): 66%.
// Per chunk of 32 gaussians: lane computes w=exp2(arg) (9 FMA + exp),
// packs f16 RNE pairs, stages once in wave-private LDS (XOR-swizzled 16B
// blocks), 4 A-frag reads feed 8 MFMAs: w*semH + w*semL (sem hi/lo carries
// precision; classes 14/15 clamp to 13 -> discarded duplicate columns).
// Epilogue: LDS 8-way reduce (own region) + one fp32 atomic/elem.
// ---------------------------------------------------------------------------
__launch_bounds__(512, 4)
__global__ void gauss_occ_main_kernel(const float* __restrict__ xyz,
                                      const float* __restrict__ p2,
                                      const _Float16* __restrict__ semH,
                                      const _Float16* __restrict__ semL,
                                      float* __restrict__ out) {
    __shared__ unsigned int wbuf[8][64][16];   // 32 KiB: per-wave 4 KiB w-tile; aliased as reduce buf

    const int tid  = threadIdx.x;
    const int lane = tid & 63;
    const int wid  = __builtin_amdgcn_readfirstlane(tid >> 6);   // wave-uniform!
    const int pg    = blockIdx.x >> 2;
    const int split = blockIdx.x & 3;
    const int slot  = split * 8 + wid;               // 0..31, uniform
    const int c0 = (slot * NCHUNK) >> 5;             // uniform
    const int c1 = ((slot + 1) * NCHUNK) >> 5;       // uniform

    const int m   = lane & 15;      // fragment row/col id
    const int mm  = (m < N_CLASSES) ? m : (N_CLASSES - 1);  // B-row clamp (cols 14/15 discarded)
    const int grp = lane >> 4;      // k-group 0..3
    const int frs = (m >> 1) & 3;   // read-side swizzle
    const int wsz = (lane >> 1) & 3;// write-side swizzle

    const int pt = pg * 64 + lane;
    const float x = xyz[pt * 3 + 0];
    const float y = xyz[pt * 3 + 1];
    const float z = xyz[pt * 3 + 2];
    const float P0 = x * x, P1 = y * y, P2 = z * z;
    const float P3 = x * y, P4 = x * z, P5 = y * z;

    f32x4 acc0 = {0.f, 0.f, 0.f, 0.f};
    f32x4 acc1 = {0.f, 0.f, 0.f, 0.f};
    f32x4 acc2 = {0.f, 0.f, 0.f, 0.f};
    f32x4 acc3 = {0.f, 0.f, 0.f, 0.f};

    unsigned int (*wrow)[16] = wbuf[wid];

    for (int c = c0; c < c1; ++c) {
        const int g0 = c * 32;   // uniform

        // B fragments: lane reads sem[clamped class][g0 + grp*8 .. +7]
        const half8 bH = *(const half8*)(semH + (size_t)mm * N_GAUSS + g0 + grp * 8);
        const half8 bL = *(const half8*)(semL + (size_t)mm * N_GAUSS + g0 + grp * 8);

        // ---- compute 32 w's, pack as f16 pairs (RNE) ----
        unsigned int wpk[16];
#pragma unroll
        for (int t = 0; t < 16; ++t) {
            const float* ga = p2 + (size_t)(g0 + 2 * t) * P2_STRIDE;  // uniform -> s_load
            const float* gb = ga + P2_STRIDE;
            float q0 = ga[9];
            q0 = fmaf(P0, ga[0], q0); q0 = fmaf(P1, ga[1], q0); q0 = fmaf(P2, ga[2], q0);
            q0 = fmaf(P3, ga[3], q0); q0 = fmaf(P4, ga[4], q0); q0 = fmaf(P5, ga[5], q0);
            q0 = fmaf(x,  ga[6], q0); q0 = fmaf(y,  ga[7], q0); q0 = fmaf(z,  ga[8], q0);
            float q1 = gb[9];
            q1 = fmaf(P0, gb[0], q1); q1 = fmaf(P1, gb[1], q1); q1 = fmaf(P2, gb[2], q1);
            q1 = fmaf(P3, gb[3], q1); q1 = fmaf(P4, gb[4], q1); q1 = fmaf(P5, gb[5], q1);
            q1 = fmaf(x,  gb[6], q1); q1 = fmaf(y,  gb[7], q1); q1 = fmaf(z,  gb[8], q1);
            half2v hv;
            hv[0] = (_Float16)__builtin_amdgcn_exp2f(q0);   // v_cvt_f16_f32 (RNE)
            hv[1] = (_Float16)__builtin_amdgcn_exp2f(q1);
            wpk[t] = __builtin_bit_cast(unsigned int, hv);
        }

        // ---- stage (once): row = lane, 16B block (sb ^ wsz) ----
#pragma unroll
        for (int sb = 0; sb < 4; ++sb) {
            *(uint4*)&wrow[lane][(sb ^ wsz) * 4] =
                make_uint4(wpk[4 * sb + 0], wpk[4 * sb + 1], wpk[4 * sb + 2], wpk[4 * sb + 3]);
        }

        // ---- A-frag reads + 8 MFMAs (compiler inserts precise lgkmcnt) ----
        const half8 a0 = *(const half8*)&wrow[ 0 + m][(grp ^ frs) * 4];
        const half8 a1 = *(const half8*)&wrow[16 + m][(grp ^ frs) * 4];
        const half8 a2 = *(const half8*)&wrow[32 + m][(grp ^ frs) * 4];
        const half8 a3 = *(const half8*)&wrow[48 + m][(grp ^ frs) * 4];
        acc0 = __builtin_amdgcn_mfma_f32_16x16x32_f16(a0, bH, acc0, 0, 0, 0);
        acc1 = __builtin_amdgcn_mfma_f32_16x16x32_f16(a1, bH, acc1, 0, 0, 0);
        acc2 = __builtin_amdgcn_mfma_f32_16x16x32_f16(a2, bH, acc2, 0, 0, 0);
        acc3 = __builtin_amdgcn_mfma_f32_16x16x32_f16(a3, bH, acc3, 0, 0, 0);
        acc0 = __builtin_amdgcn_mfma_f32_16x16x32_f16(a0, bL, acc0, 0, 0, 0);
        acc1 = __builtin_amdgcn_mfma_f32_16x16x32_f16(a1, bL, acc1, 0, 0, 0);
        acc2 = __builtin_amdgcn_mfma_f32_16x16x32_f16(a2, bL, acc2, 0, 0, 0);
        acc3 = __builtin_amdgcn_mfma_f32_16x16x32_f16(a3, bL, acc3, 0, 0, 0);
    }

    // ---- epilogue: dump acc into own LDS region, 8-way reduce, atomics ----
    float* red = (float*)&wbuf[0][0][0];   // [8][64][16] f32; wave wid's region == its wbuf
#pragma unroll
    for (int i = 0; i < 4; ++i) {
        red[wid * 1024 + ( 0 + grp * 4 + i) * 16 + m] = acc0[i];
        red[wid * 1024 + (16 + grp * 4 + i) * 16 + m] = acc1[i];
        red[wid * 1024 + (32 + grp * 4 + i) * 16 + m] = acc2[i];
        red[wid * 1024 + (48 + grp * 4 + i) * 16 + m] = acc3[i];
    }
    __syncthreads();

    for (int idx = tid; idx < 64 * N_CLASSES; idx += 512) {
        const int l = idx / N_CLASSES;
        const int cc = idx - l * N_CLASSES;
        float s = 0.0f;
#pragma unroll
        for (int wq = 0; wq < 8; ++wq) s += red[wq * 1024 + l * 16 + cc];
        unsafeAtomicAdd(&out[(pg * 64 + l) * N_CLASSES + cc], s);
    }
}

extern "C" void kernel_launch(void* const* d_in, const int* in_sizes, int n_in,
                              void* d_out, int out_size, void* d_ws, size_t ws_size,
                              hipStream_t stream) {
    const float* xyz       = (const float*)d_in[0];
    const float* means     = (const float*)d_in[1];
    const float* scales    = (const float*)d_in[2];
    const float* rotations = (const float*)d_in[3];
    const float* opacities = (const float*)d_in[4];
    const float* semantics = (const float*)d_in[5];
    float* out = (float*)d_out;

    float*    p2   = (float*)((char*)d_ws + WS_P2_OFF);
    _Float16* semH = (_Float16*)((char*)d_ws + WS_SEMH_OFF);
    _Float16* semL = (_Float16*)((char*)d_ws + WS_SEML_OFF);

    (void)hipMemsetAsync(d_out, 0, (size_t)out_size * sizeof(float), stream);

    hipLaunchKernelGGL(gauss_prep_kernel,
                       dim3((N_GAUSS + 255) / 256), dim3(256), 0, stream,
                       means, scales, rotations, opacities, semantics, p2, semH, semL);

    hipLaunchKernelGGL(gauss_occ_main_kernel,
                       dim3(256 * 4), dim3(512), 0, stream,
                       xyz, p2, semH, semL, out);
}